// Round 8
// baseline (28263.171 us; speedup 1.0000x reference)
//
#include <hip/hip_runtime.h>
#include <hip/hip_bf16.h>
#include <stdint.h>

typedef unsigned short u16;
typedef __attribute__((ext_vector_type(8))) short short8;
typedef __attribute__((ext_vector_type(8))) _Float16 half8;
typedef __attribute__((ext_vector_type(4))) float f32x4;

#define B_   128
#define TL_  400
#define AL_  50
#define QL_  32
#define E_   300
#define V_   30000
#define EP_  320     // E padded (K for gi GEMM)
#define K2P_ 640     // 2H padded (text_rep stride)
#define KDP_ 1216    // 1200 padded (K for dec + out GEMM)
#define NDP_ 1920    // 1800 padded (dec gi+gh cols)
#define MT_  51200   // B*TL
#define MA_  6400    // B*AL
#define MD_  3968    // 31*128
#define WPT_ (10*1024*32)   // per-task WhhP tiled size (elems)

static __device__ __forceinline__ float bf2f(u16 u) {
    union { float f; unsigned v; } c; c.v = ((unsigned)u) << 16; return c.f;
}
static __device__ __forceinline__ u16 f2bf(float f) {
    union { float f; unsigned v; } c; c.f = f;
    unsigned r = c.v + 0x7FFF + ((c.v >> 16) & 1);
    return (u16)(r >> 16);
}
static __device__ __forceinline__ u16 f2h_bits(float f) {
    _Float16 h = (_Float16)f; u16 u; __builtin_memcpy(&u, &h, 2); return u;
}
static __device__ __forceinline__ float sigm(float x) { return 1.f / (1.f + __expf(-x)); }

// ---------------------------------------------------------------- transpose+convert
// dst[(n0+n)*ldbt + k0+k] = bf16(src[k*N + n])
__global__ __launch_bounds__(256) void transpose_cvt(const float* __restrict__ src, int K, int N,
                                                     u16* __restrict__ dst, int ldbt, int n0, int k0) {
    __shared__ float tile[32][33];
    int kb = blockIdx.x * 32, nb = blockIdx.y * 32;
    int tx = threadIdx.x & 31, ty = threadIdx.x >> 5;
    for (int i = ty; i < 32; i += 8) {
        int k = kb + i, n = nb + tx;
        tile[i][tx] = (k < K && n < N) ? src[(size_t)k * N + n] : 0.f;
    }
    __syncthreads();
    for (int i = ty; i < 32; i += 8) {
        int n = nb + i, k = kb + tx;
        if (n < N && k < K) dst[(size_t)(n0 + n) * ldbt + k0 + k] = f2bf(tile[tx][i]);
    }
}

// WhhPt[task][kt][c(1024)][kk(32)] = FP16 of Whh[k][g*300+j] with c = g*304 + j  (tile-aligned
// gate-major layout: the r/z/n triplet for a j lives at the same lane across 3 tiles).
// k==300 row = bhh; k>300, j>=300, c>=912 are zero.
__global__ __launch_bounds__(320) void prep_whh(const float* __restrict__ W0, const float* __restrict__ W1,
                                                const float* __restrict__ W2, const float* __restrict__ W3,
                                                const float* __restrict__ b0, const float* __restrict__ b1,
                                                const float* __restrict__ b2, const float* __restrict__ b3,
                                                u16* __restrict__ dst) {
    int c = blockIdx.x, task = blockIdx.y;
    const float* W = task == 0 ? W0 : task == 1 ? W1 : task == 2 ? W2 : W3;
    const float* b = task == 0 ? b0 : task == 1 ? b1 : task == 2 ? b2 : b3;
    int k = threadIdx.x;
    float val = 0.f;
    if (c < 912) {
        int g = c / 304, j = c % 304;
        if (j < 300) {
            if (k < 300) val = W[(size_t)k * 900 + g * 300 + j];
            else if (k == 300) val = b[g * 300 + j];
        }
    }
    dst[(size_t)task * WPT_ + ((size_t)(k >> 5) * 1024 + c) * 32 + (k & 31)] = f2h_bits(val);
}

__global__ __launch_bounds__(256) void build_dec_bias(const float* __restrict__ bih,
                                                      const float* __restrict__ bhh,
                                                      float* __restrict__ bias) {
    int i = blockIdx.x * 256 + threadIdx.x;
    if (i < 900) bias[i] = bih[i];
    else if (i < 1800) bias[i] = bhh[i - 900];
    else if (i < NDP_) bias[i] = 0.f;
}

// ---------------------------------------------------------------- embedding gathers
__global__ __launch_bounds__(256) void gather_rows(const int* __restrict__ idx, const float* __restrict__ emb,
                                                   u16* __restrict__ dst, int ldd) {
    int r = blockIdx.x;
    int id = idx[r];
    const float* e = emb + (size_t)id * E_;
    for (int i = threadIdx.x; i < E_; i += 256) dst[(size_t)r * ldd + i] = f2bf(e[i]);
}

__global__ __launch_bounds__(256) void gather_q(const int* __restrict__ question, const float* __restrict__ emb,
                                                u16* __restrict__ A_dec, u16* __restrict__ A_out) {
    int r = blockIdx.x;            // t*128 + b
    int t = r >> 7, b = r & 127;
    int id = question[b * QL_ + t];
    const float* e = emb + (size_t)id * E_;
    for (int i = threadIdx.x; i < E_; i += 256) {
        u16 u = f2bf(e[i]);
        A_dec[(size_t)r * KDP_ + i] = u;
        A_out[(size_t)r * KDP_ + 900 + i] = u;
    }
}

// ---------------------------------------------------------------- bf16 MFMA GEMM, C = A * Bt^T
template <int MODE>
__global__ __launch_bounds__(256) void gemm_bt(const u16* __restrict__ A, int lda,
                                               const u16* __restrict__ Bt, int ldb,
                                               void* __restrict__ Cv, int ldc, int Nreal,
                                               const float* __restrict__ bias, int Kpad) {
    __shared__ u16 lA[128 * 32];
    __shared__ u16 lB[128 * 32];
    const int tid = threadIdx.x;
    const int bn = blockIdx.x, bm = blockIdx.y;
    const long row0 = (long)bm * 128;
    const u16* Ab = A + row0 * lda;
    const u16* Bb = Bt + (long)bn * 128 * ldb;
    const int lane = tid & 63, wave = tid >> 6;
    const int wr = wave >> 1, wc = wave & 1;
    const int lr = lane & 15, ko = (lane >> 4) * 8;
    f32x4 acc[4][4] = {};

    for (int k0 = 0; k0 < Kpad; k0 += 32) {
#pragma unroll
        for (int i = 0; i < 2; ++i) {
            const int c = tid + 256 * i;
            const int e = c * 8;
            const int r = e >> 5, col = e & 31;
            __builtin_amdgcn_global_load_lds(
                (const __attribute__((address_space(1))) void*)(Ab + (long)r * lda + k0 + col),
                (__attribute__((address_space(3))) void*)(&lA[e]), 16, 0, 0);
            __builtin_amdgcn_global_load_lds(
                (const __attribute__((address_space(1))) void*)(Bb + (long)r * ldb + k0 + col),
                (__attribute__((address_space(3))) void*)(&lB[e]), 16, 0, 0);
        }
        __syncthreads();
        short8 af[4], bfr[4];
#pragma unroll
        for (int i = 0; i < 4; ++i) {
            af[i]  = *(const short8*)&lA[(wr * 64 + i * 16 + lr) * 32 + ko];
            bfr[i] = *(const short8*)&lB[(wc * 64 + i * 16 + lr) * 32 + ko];
        }
#pragma unroll
        for (int i = 0; i < 4; ++i)
#pragma unroll
            for (int j = 0; j < 4; ++j)
                acc[i][j] = __builtin_amdgcn_mfma_f32_16x16x32_bf16(af[i], bfr[j], acc[i][j], 0, 0, 0);
        __syncthreads();
    }

    const int r4 = (lane >> 4) * 4;
    const int cl = lane & 15;
#pragma unroll
    for (int i = 0; i < 4; ++i) {
#pragma unroll
        for (int j = 0; j < 4; ++j) {
            const int colg = bn * 128 + wc * 64 + j * 16 + cl;
            if (colg >= Nreal) continue;
            const float bv = bias ? bias[colg] : 0.f;
#pragma unroll
            for (int v = 0; v < 4; ++v) {
                const long rowg = row0 + wr * 64 + i * 16 + r4 + v;
                const float val = acc[i][j][v] + bv;
                if (MODE == 0) {
                    ((float*)Cv)[rowg * (long)ldc + colg] = val;
                } else if (MODE == 1) {
                    ((u16*)Cv)[rowg * (long)ldc + colg] = f2bf(val);
                } else {
                    const int tt = (int)(rowg >> 7), bb = (int)(rowg & 127);
                    ((float*)Cv)[((long)bb * QL_ + tt + 1) * (long)V_ + colg] = val;
                }
            }
        }
    }
}

// ---------------------------------------------------------------- persistent encoder (v2)
// 16 blocks: task = bid>>2 (0 text-f, 1 text-b, 2 ans-f, 3 ans-b), bslice = bid&3 (32 batches).
// Per step: gh+bhh = MFMA_f16( [h_hi|h_lo][32 x 320], WhhP[1024 x 320]^T ).
// Structure is gemm_bt-shaped: single-buffered k-loop {issue loads; __syncthreads; MFMA;
// __syncthreads}. Gate-major W layout (c = gate*304 + j) makes the r/z/n triplet land in the
// same lane/reg across 3 tiles -> gates are pure per-thread math. Thread owns
// (batch = wm*16+q*4+v, j = G*16+jl) persistently.
// INIT-RACE FIX (r8): the bias cell hHi[row][k=300]=1.0 for rows 2..31 was zeroed by threads in
// OTHER waves with no ordering (zero-loop and bias-write both preceded one barrier) -> bhh
// silently dropped for a timing-dependent subset of batch rows -> the invariant ~0.15 error of
// r2-r7. A __syncthreads() between zero-fill and bias write orders them.
__global__ __launch_bounds__(512) void enc_persist(
        const u16* __restrict__ Wp_all,
        const u16* __restrict__ gi_tf, const u16* __restrict__ gi_tb,
        const u16* __restrict__ gi_af, const u16* __restrict__ gi_ab,
        u16* __restrict__ text_rep, float* __restrict__ h_fin) {
    const int task = blockIdx.x >> 2, bslice = blockIdx.x & 3;
    const u16* Wp = Wp_all + (size_t)task * WPT_;
    const u16* gi; int T, Tloop, rev;
    if (task == 0)      { gi = gi_tf; T = 400; Tloop = 400; rev = 0; }
    else if (task == 1) { gi = gi_tb; T = 400; Tloop = 400; rev = 1; }
    else if (task == 2) { gi = gi_af; T = 50;  Tloop = 50;  rev = 0; }
    else                { gi = gi_ab; T = 50;  Tloop = 1;   rev = 1; }

    __shared__ u16 bT[1024 * 32];       // 64KB: single-buffered W(fp16) k-tile (all 1024 cols)
    __shared__ u16 hHi[10 * 32 * 32];   // 20KB: h_hi fp16, [kt][row][kk]; k=300 = bias col 1.0
    __shared__ u16 hLo[10 * 32 * 32];   // 20KB: h_lo fp16

    const int tid = threadIdx.x, lane = tid & 63, wave = tid >> 6;
    const int wm = wave >> 2, wn = wave & 3;       // wm: batch half, wn: column-group lane
    const int lr = lane & 15, ko8 = (lane >> 4) * 8;
    const int q = lane >> 4, jl = lane & 15;

    for (int i = tid; i < 10240; i += 512) { hHi[i] = 0; hLo[i] = 0; }
    __syncthreads();   // RACE FIX: zero-fill must be globally visible before the bias write
    if (tid < 32) hHi[(9 * 32 + tid) * 32 + 12] = 0x3C00;  // fp16(1.0) at k=300
    __syncthreads();

    float hprev[20];
#pragma unroll
    for (int i = 0; i < 20; ++i) hprev[i] = 0.f;

    for (int t = 0; t < Tloop; ++t) {
        const int te = rev ? (T - 1 - t) : t;
        f32x4 acc[15] = {};
        for (int kt = 0; kt < 10; ++kt) {
            // stage W k-tile (64KB) — gemm_bt pattern: issue, then one barrier drains
#pragma unroll
            for (int r = 0; r < 8; ++r) {
                int idx = r * 512 + tid;
                __builtin_amdgcn_global_load_lds(
                    (const __attribute__((address_space(1))) void*)(Wp + (size_t)kt * 32768 + idx * 8),
                    (__attribute__((address_space(3))) void*)(&bT[idx * 8]), 16, 0, 0);
            }
            __syncthreads();
            half8 afh = *(const half8*)&hHi[((kt * 32) + wm * 16 + lr) * 32 + ko8];
            half8 afl = *(const half8*)&hLo[((kt * 32) + wm * 16 + lr) * 32 + ko8];
#pragma unroll
            for (int gx = 0; gx < 5; ++gx) {
                const int G = wn + 4 * gx;
                if (G < 19) {
#pragma unroll
                    for (int gate = 0; gate < 3; ++gate) {
                        const int tn = 19 * gate + G;
                        half8 bf = *(const half8*)&bT[(tn * 16 + lr) * 32 + ko8];
                        acc[gx * 3 + gate] = __builtin_amdgcn_mfma_f32_16x16x32_f16(afh, bf, acc[gx * 3 + gate], 0, 0, 0);
                        acc[gx * 3 + gate] = __builtin_amdgcn_mfma_f32_16x16x32_f16(afl, bf, acc[gx * 3 + gate], 0, 0, 0);
                    }
                }
            }
            __syncthreads();
        }
        // ---- gates: pure per-thread (triplet is in-thread thanks to gate-major W layout)
#pragma unroll
        for (int gx = 0; gx < 5; ++gx) {
            const int G = wn + 4 * gx;
            if (G >= 19) continue;
            const int j = G * 16 + jl;
            if (j >= 300) continue;
#pragma unroll
            for (int v = 0; v < 4; ++v) {
                const int batch = wm * 16 + q * 4 + v;
                const int bglob = bslice * 32 + batch;
                const u16* gp = gi + ((size_t)bglob * T + te) * 900;
                const float ar = acc[gx * 3 + 0][v];
                const float az = acc[gx * 3 + 1][v];
                const float an = acc[gx * 3 + 2][v];
                float r_ = sigm(bf2f(gp[j]) + ar);
                float z_ = sigm(bf2f(gp[j + 300]) + az);
                float x = bf2f(gp[j + 600]) + r_ * an;
                x = fminf(fmaxf(x, -15.f), 15.f);
                float e = __expf(2.f * x);
                float n_ = (e - 1.f) / (e + 1.f);
                float hn = (1.f - z_) * n_ + z_ * hprev[gx * 4 + v];
                hprev[gx * 4 + v] = hn;
                _Float16 hh = (_Float16)hn;
                float hhf = (float)hh;
                _Float16 hl = (_Float16)(hn - hhf);
                u16 uhh, uhl;
                __builtin_memcpy(&uhh, &hh, 2);
                __builtin_memcpy(&uhl, &hl, 2);
                const int hidx = ((j >> 5) * 32 + batch) * 32 + (j & 31);
                hHi[hidx] = uhh;
                hLo[hidx] = uhl;
                if (task < 2) text_rep[((size_t)bglob * TL_ + te) * K2P_ + task * 300 + j] = f2bf(hn);
            }
        }
        __syncthreads();   // h writes visible before next t's kt=0 A-reads
    }
    if (task >= 2) {
#pragma unroll
        for (int gx = 0; gx < 5; ++gx) {
            const int G = wn + 4 * gx; if (G >= 19) continue;
            const int j = G * 16 + jl; if (j >= 300) continue;
#pragma unroll
            for (int v = 0; v < 4; ++v) {
                const int bglob = bslice * 32 + wm * 16 + q * 4 + v;
                h_fin[(size_t)(task - 2) * 38400 + (size_t)bglob * 300 + j] = hprev[gx * 4 + v];
            }
        }
    }
}

// ---------------------------------------------------------------- hidden0 = ans_rep[:,-1,:] @ trans_W + trans_b
__global__ __launch_bounds__(256) void trans_hidden(const float* __restrict__ h_fin,
                                                    const float* __restrict__ trans_W,
                                                    const float* __restrict__ trans_b,
                                                    float* __restrict__ h_dec, u16* __restrict__ A_dec0) {
    int b = blockIdx.x, tid = threadIdx.x;
    __shared__ float si[600];
    const float* af = h_fin + (size_t)b * 300;            // ans-fwd final
    const float* ab = h_fin + 38400 + (size_t)b * 300;    // ans-bwd (single step)
    for (int i = tid; i < 300; i += 256) { si[i] = af[i]; si[300 + i] = ab[i]; }
    __syncthreads();
    for (int jj = tid; jj < 300; jj += 256) {
        float acc = trans_b[jj];
        for (int k = 0; k < 600; ++k) acc += si[k] * trans_W[k * 300 + jj];
        h_dec[(size_t)b * 300 + jj] = acc;
        A_dec0[(size_t)b * KDP_ + 900 + jj] = f2bf(acc);
    }
}

// ---------------------------------------------------------------- attention (one block per batch row)
__global__ __launch_bounds__(256) void attn_step(int t, const float* __restrict__ h_dec,
                                                 const float* __restrict__ Wk, const float* __restrict__ av,
                                                 const float* __restrict__ qproj, const u16* __restrict__ text_rep,
                                                 u16* __restrict__ A_dec_t, u16* __restrict__ A_out) {
    const int b = blockIdx.x, tid = threadIdx.x, lane = tid & 63, wave = tid >> 6;
    __shared__ float sh[300], hwk[300], sc[400], red[8];
    for (int i = tid; i < 300; i += 256) sh[i] = h_dec[(size_t)b * 300 + i];
    __syncthreads();
    for (int jj = tid; jj < 300; jj += 256) {
        float acc = 0.f;
        for (int k = 0; k < 300; ++k) acc += sh[k] * Wk[k * 300 + jj];
        hwk[jj] = acc;
    }
    __syncthreads();
    for (int s = wave; s < 400; s += 4) {
        const float* qp = qproj + ((size_t)b * TL_ + s) * 300;
        float p = 0.f;
        for (int d = lane; d < 300; d += 64) {
            float e = qp[d] + hwk[d];
            e = fminf(fmaxf(e, -15.f), 15.f);
            float ex = __expf(2.f * e);
            p += ((ex - 1.f) / (ex + 1.f)) * av[d];
        }
#pragma unroll
        for (int off = 32; off > 0; off >>= 1) p += __shfl_down(p, off);
        if (lane == 0) sc[s] = p;
    }
    __syncthreads();
    float m = -1e30f;
    for (int i = tid; i < 400; i += 256) m = fmaxf(m, sc[i]);
#pragma unroll
    for (int off = 32; off > 0; off >>= 1) m = fmaxf(m, __shfl_down(m, off));
    if (lane == 0) red[wave] = m;
    __syncthreads();
    m = fmaxf(fmaxf(red[0], red[1]), fmaxf(red[2], red[3]));
    float ssum = 0.f;
    for (int i = tid; i < 400; i += 256) { float e = __expf(sc[i] - m); sc[i] = e; ssum += e; }
#pragma unroll
    for (int off = 32; off > 0; off >>= 1) ssum += __shfl_down(ssum, off);
    if (lane == 0) red[4 + wave] = ssum;
    __syncthreads();
    const float inv = 1.f / (red[4] + red[5] + red[6] + red[7]);
    for (int e0 = tid; e0 < 600; e0 += 256) {
        float acc = 0.f;
        for (int s = 0; s < 400; ++s) acc += sc[s] * bf2f(text_rep[((size_t)b * TL_ + s) * K2P_ + e0]);
        u16 wv = f2bf(acc * inv);
        A_dec_t[(size_t)b * KDP_ + 300 + e0] = wv;
        A_out[((size_t)t * 128 + b) * KDP_ + 300 + e0] = wv;
    }
}

// ---------------------------------------------------------------- decoder GRU gates
__global__ __launch_bounds__(256) void dec_gate(int t, const float* __restrict__ g_all,
                                                float* __restrict__ h_dec,
                                                u16* __restrict__ A_dec, u16* __restrict__ A_out) {
    int idx = blockIdx.x * 256 + threadIdx.x;
    if (idx >= 128 * 300) return;
    int b = idx / 300, j = idx % 300;
    const float* g = g_all + (size_t)b * NDP_;
    float r = sigm(g[j] + g[900 + j]);
    float z = sigm(g[300 + j] + g[1200 + j]);
    float n = tanhf(g[600 + j] + r * g[1500 + j]);
    float hp = h_dec[idx];
    float hn = (1.f - z) * n + z * hp;
    h_dec[idx] = hn;
    u16 u = f2bf(hn);
    A_out[((size_t)t * 128 + b) * KDP_ + j] = u;
    if (t < 30) A_dec[((size_t)(t + 1) * 128 + b) * KDP_ + 900 + j] = u;
}

__global__ __launch_bounds__(256) void zero_t0(float* __restrict__ out) {
    int i = blockIdx.x * 256 + threadIdx.x;
    if (i < 128 * V_) {
        int b = i / V_, v = i % V_;
        out[(size_t)b * QL_ * V_ + v] = 0.f;
    }
}

// ================================================================ host
extern "C" void kernel_launch(void* const* d_in, const int* in_sizes, int n_in,
                              void* d_out, int out_size, void* d_ws, size_t ws_size,
                              hipStream_t stream) {
    (void)in_sizes; (void)n_in; (void)out_size;
    const int*   text      = (const int*)d_in[0];
    const int*   answer    = (const int*)d_in[1];
    const int*   question  = (const int*)d_in[2];
    const float* embedding = (const float*)d_in[3];
    const float* te_Wih_f = (const float*)d_in[4],  *te_Whh_f = (const float*)d_in[5];
    const float* te_bih_f = (const float*)d_in[6],  *te_bhh_f = (const float*)d_in[7];
    const float* te_Wih_b = (const float*)d_in[8],  *te_Whh_b = (const float*)d_in[9];
    const float* te_bih_b = (const float*)d_in[10], *te_bhh_b = (const float*)d_in[11];
    const float* ae_Wih_f = (const float*)d_in[12], *ae_Whh_f = (const float*)d_in[13];
    const float* ae_bih_f = (const float*)d_in[14], *ae_bhh_f = (const float*)d_in[15];
    const float* ae_Wih_b = (const float*)d_in[16], *ae_Whh_b = (const float*)d_in[17];
    const float* ae_bih_b = (const float*)d_in[18], *ae_bhh_b = (const float*)d_in[19];
    const float* trans_W  = (const float*)d_in[20], *trans_b  = (const float*)d_in[21];
    const float* attn_Wk  = (const float*)d_in[22], *attn_Wq  = (const float*)d_in[23];
    const float* attn_b   = (const float*)d_in[24], *attn_v   = (const float*)d_in[25];
    const float* dec_Wih  = (const float*)d_in[26], *dec_Whh  = (const float*)d_in[27];
    const float* dec_bih  = (const float*)d_in[28], *dec_bhh  = (const float*)d_in[29];
    const float* out_W    = (const float*)d_in[30], *out_b    = (const float*)d_in[31];
    float* out = (float*)d_out;

    // ---- workspace carve
    char* w = (char*)d_ws; size_t off = 0;
    auto alloc = [&](size_t bytes) -> void* { void* p = w + off; off += (bytes + 255) & ~(size_t)255; return p; };
    u16* WihT_tf = (u16*)alloc(1024 * EP_ * 2);
    u16* WihT_tb = (u16*)alloc(1024 * EP_ * 2);
    u16* WihT_af = (u16*)alloc(1024 * EP_ * 2);
    u16* WihT_ab = (u16*)alloc(1024 * EP_ * 2);
    u16* WqT     = (u16*)alloc(384 * K2P_ * 2);
    u16* outWT   = (u16*)alloc((size_t)30080 * KDP_ * 2);
    u16* decBT   = (u16*)alloc((size_t)NDP_ * KDP_ * 2);
    float* decBias = (float*)alloc(NDP_ * 4);
    u16* WhhPt   = (u16*)alloc((size_t)4 * WPT_ * 2);
    u16* textEmb = (u16*)alloc((size_t)MT_ * EP_ * 2);
    u16* ansEmb  = (u16*)alloc((size_t)MA_ * EP_ * 2);
    u16* gi_tf   = (u16*)alloc((size_t)MT_ * 900 * 2);
    u16* gi_tb   = (u16*)alloc((size_t)MT_ * 900 * 2);
    u16* gi_af   = (u16*)alloc((size_t)MA_ * 900 * 2);
    u16* gi_ab   = (u16*)alloc((size_t)MA_ * 900 * 2);
    u16* text_rep = (u16*)alloc((size_t)MT_ * K2P_ * 2);
    float* qproj = (float*)alloc((size_t)MT_ * 300 * 4);
    float* h_fin = (float*)alloc((size_t)2 * 128 * 300 * 4);
    float* h_dec = (float*)alloc((size_t)128 * 300 * 4);
    u16* A_dec   = (u16*)alloc((size_t)MD_ * KDP_ * 2);
    u16* A_out   = (u16*)alloc((size_t)MD_ * KDP_ * 2);
    float* gi_gh = (float*)alloc((size_t)128 * NDP_ * 4);
    const size_t need = off;
    size_t zbytes = need <= ws_size ? need : ws_size;

    hipMemsetAsync(d_ws, 0, zbytes, stream);

    // ---- weight prep (gi path: r1's UNPERMUTED layout)
    transpose_cvt<<<dim3(10, 29), 256, 0, stream>>>(te_Wih_f, 300, 900, WihT_tf, EP_, 0, 0);
    transpose_cvt<<<dim3(10, 29), 256, 0, stream>>>(te_Wih_b, 300, 900, WihT_tb, EP_, 0, 0);
    transpose_cvt<<<dim3(10, 29), 256, 0, stream>>>(ae_Wih_f, 300, 900, WihT_af, EP_, 0, 0);
    transpose_cvt<<<dim3(10, 29), 256, 0, stream>>>(ae_Wih_b, 300, 900, WihT_ab, EP_, 0, 0);
    prep_whh<<<dim3(1024, 4), 320, 0, stream>>>(te_Whh_f, te_Whh_b, ae_Whh_f, ae_Whh_b,
                                                te_bhh_f, te_bhh_b, ae_bhh_f, ae_bhh_b, WhhPt);
    transpose_cvt<<<dim3(19, 10), 256, 0, stream>>>(attn_Wq, 600, 300, WqT, K2P_, 0, 0);
    transpose_cvt<<<dim3(38, 938), 256, 0, stream>>>(out_W, 1200, V_, outWT, KDP_, 0, 0);
    transpose_cvt<<<dim3(29, 29), 256, 0, stream>>>(dec_Wih, 900, 900, decBT, KDP_, 0, 0);
    transpose_cvt<<<dim3(10, 29), 256, 0, stream>>>(dec_Whh, 300, 900, decBT, KDP_, 900, 900);
    build_dec_bias<<<8, 256, 0, stream>>>(dec_bih, dec_bhh, decBias);

    // ---- embedding gathers
    gather_rows<<<MT_, 256, 0, stream>>>(text, embedding, textEmb, EP_);
    gather_rows<<<MA_, 256, 0, stream>>>(answer, embedding, ansEmb, EP_);
    gather_q<<<MD_, 256, 0, stream>>>(question, embedding, A_dec, A_out);

    // ---- gi = x @ Wih + bih  (UNPERMUTED columns, raw bih bias — r1 configuration)
    gemm_bt<1><<<dim3(8, 400), 256, 0, stream>>>(textEmb, EP_, WihT_tf, EP_, gi_tf, 900, 900, te_bih_f, EP_);
    gemm_bt<1><<<dim3(8, 400), 256, 0, stream>>>(textEmb, EP_, WihT_tb, EP_, gi_tb, 900, 900, te_bih_b, EP_);
    gemm_bt<1><<<dim3(8, 50),  256, 0, stream>>>(ansEmb, EP_, WihT_af, EP_, gi_af, 900, 900, ae_bih_f, EP_);
    gemm_bt<1><<<dim3(8, 50),  256, 0, stream>>>(ansEmb, EP_, WihT_ab, EP_, gi_ab, 900, 900, ae_bih_b, EP_);

    // ---- persistent encoder (16 independent blocks)
    enc_persist<<<16, 512, 0, stream>>>(WhhPt, gi_tf, gi_tb, gi_af, gi_ab, text_rep, h_fin);

    // ---- decoder init + qproj
    trans_hidden<<<128, 256, 0, stream>>>(h_fin, trans_W, trans_b, h_dec, A_dec);
    gemm_bt<0><<<dim3(3, 400), 256, 0, stream>>>(text_rep, K2P_, WqT, K2P_, qproj, 300, 300, attn_b, K2P_);

    // ---- decode loop
    for (int t = 0; t < QL_ - 1; ++t) {
        attn_step<<<128, 256, 0, stream>>>(t, h_dec, attn_Wk, attn_v, qproj, text_rep,
                                           A_dec + (size_t)t * 128 * KDP_, A_out);
        gemm_bt<0><<<dim3(15, 1), 256, 0, stream>>>(A_dec + (size_t)t * 128 * KDP_, KDP_,
                                                    decBT, KDP_, gi_gh, NDP_, 1800, decBias, KDP_);
        dec_gate<<<150, 256, 0, stream>>>(t, gi_gh, h_dec, A_dec, A_out);
    }

    // ---- logits
    gemm_bt<2><<<dim3(235, 31), 256, 0, stream>>>(A_out, KDP_, outWT, KDP_, d_out, 0, V_, out_b, KDP_);
    zero_t0<<<(128 * V_ + 255) / 256, 256, 0, stream>>>(out);
}

// Round 9
// 21281.902 us; speedup vs baseline: 1.3280x; 1.3280x over previous
//
#include <hip/hip_runtime.h>
#include <hip/hip_bf16.h>
#include <stdint.h>

typedef unsigned short u16;
typedef __attribute__((ext_vector_type(8))) short short8;
typedef __attribute__((ext_vector_type(8))) _Float16 half8;
typedef __attribute__((ext_vector_type(4))) float f32x4;
typedef __attribute__((ext_vector_type(4))) unsigned short u16x4;

#define B_   128
#define TL_  400
#define AL_  50
#define QL_  32
#define E_   300
#define V_   30000
#define EP_  320     // E padded (K for gi GEMM; col 300 = ones for bih fold)
#define K2P_ 640     // 2H padded (text_rep stride)
#define KDP_ 1216    // 1200 padded (K for dec + out GEMM)
#define NDP_ 1920    // 1800 padded (dec gi+gh cols)
#define MT_  51200   // B*TL
#define MA_  6400    // B*AL
#define MD_  3968    // 31*128
#define WPT_ (10*1024*32)   // per-task WhhP tiled size (elems)

static __device__ __forceinline__ float bf2f(u16 u) {
    union { float f; unsigned v; } c; c.v = ((unsigned)u) << 16; return c.f;
}
static __device__ __forceinline__ u16 f2bf(float f) {
    union { float f; unsigned v; } c; c.f = f;
    unsigned r = c.v + 0x7FFF + ((c.v >> 16) & 1);
    return (u16)(r >> 16);
}
static __device__ __forceinline__ u16 f2h_bits(float f) {
    _Float16 h = (_Float16)f; u16 u; __builtin_memcpy(&u, &h, 2); return u;
}
static __device__ __forceinline__ float sigm(float x) { return 1.f / (1.f + __expf(-x)); }

// ---------------------------------------------------------------- transpose+convert
// dst[(n0+n)*ldbt + k0+k] = bf16(src[k*N + n])
__global__ __launch_bounds__(256) void transpose_cvt(const float* __restrict__ src, int K, int N,
                                                     u16* __restrict__ dst, int ldbt, int n0, int k0) {
    __shared__ float tile[32][33];
    int kb = blockIdx.x * 32, nb = blockIdx.y * 32;
    int tx = threadIdx.x & 31, ty = threadIdx.x >> 5;
    for (int i = ty; i < 32; i += 8) {
        int k = kb + i, n = nb + tx;
        tile[i][tx] = (k < K && n < N) ? src[(size_t)k * N + n] : 0.f;
    }
    __syncthreads();
    for (int i = ty; i < 32; i += 8) {
        int n = nb + i, k = kb + tx;
        if (n < N && k < K) dst[(size_t)(n0 + n) * ldbt + k0 + k] = f2bf(tile[tx][i]);
    }
}

// WihT[n][300] = bih[n]  (bias folded into K via ones-column of the embedding matrix)
__global__ __launch_bounds__(256) void set_wih_bias(u16* __restrict__ dst, const float* __restrict__ b) {
    int n = blockIdx.x * 256 + threadIdx.x;
    if (n < 900) dst[(size_t)n * EP_ + 300] = f2bf(b[n]);
}

// WhhPt[task][kt][c(1024)][kk(32)] = FP16 of Whh[k][g*300+j] with c = g*304 + j  (tile-aligned
// gate-major layout). k==300 row = bhh; k>300, j>=300, c>=912 are zero.
__global__ __launch_bounds__(320) void prep_whh(const float* __restrict__ W0, const float* __restrict__ W1,
                                                const float* __restrict__ W2, const float* __restrict__ W3,
                                                const float* __restrict__ b0, const float* __restrict__ b1,
                                                const float* __restrict__ b2, const float* __restrict__ b3,
                                                u16* __restrict__ dst) {
    int c = blockIdx.x, task = blockIdx.y;
    const float* W = task == 0 ? W0 : task == 1 ? W1 : task == 2 ? W2 : W3;
    const float* b = task == 0 ? b0 : task == 1 ? b1 : task == 2 ? b2 : b3;
    int k = threadIdx.x;
    float val = 0.f;
    if (c < 912) {
        int g = c / 304, j = c % 304;
        if (j < 300) {
            if (k < 300) val = W[(size_t)k * 900 + g * 300 + j];
            else if (k == 300) val = b[g * 300 + j];
        }
    }
    dst[(size_t)task * WPT_ + ((size_t)(k >> 5) * 1024 + c) * 32 + (k & 31)] = f2h_bits(val);
}

__global__ __launch_bounds__(256) void build_dec_bias(const float* __restrict__ bih,
                                                      const float* __restrict__ bhh,
                                                      float* __restrict__ bias) {
    int i = blockIdx.x * 256 + threadIdx.x;
    if (i < 900) bias[i] = bih[i];
    else if (i < 1800) bias[i] = bhh[i - 900];
    else if (i < NDP_) bias[i] = 0.f;
}

// ---------------------------------------------------------------- embedding gathers
// TIME-MAJOR: dst row r = t*128 + b  <-  emb[idx[b*T + t]]; col 300 = 1.0 (bias ones-column)
__global__ __launch_bounds__(256) void gather_tm(const int* __restrict__ idx, const float* __restrict__ emb,
                                                 u16* __restrict__ dst, int T) {
    int r = blockIdx.x;
    int t = r >> 7, b = r & 127;
    int id = idx[b * T + t];
    const float* e = emb + (size_t)id * E_;
    for (int i = threadIdx.x; i < E_; i += 256) dst[(size_t)r * EP_ + i] = f2bf(e[i]);
    if (threadIdx.x == 0) dst[(size_t)r * EP_ + 300] = 0x3F80;   // bf16(1.0)
}

__global__ __launch_bounds__(256) void gather_q(const int* __restrict__ question, const float* __restrict__ emb,
                                                u16* __restrict__ A_dec, u16* __restrict__ A_out) {
    int r = blockIdx.x;            // t*128 + b
    int t = r >> 7, b = r & 127;
    int id = question[b * QL_ + t];
    const float* e = emb + (size_t)id * E_;
    for (int i = threadIdx.x; i < E_; i += 256) {
        u16 u = f2bf(e[i]);
        A_dec[(size_t)r * KDP_ + i] = u;
        A_out[(size_t)r * KDP_ + 900 + i] = u;
    }
}

// ---------------------------------------------------------------- bf16 MFMA GEMM, C = A * Bt^T
template <int MODE>
__global__ __launch_bounds__(256) void gemm_bt(const u16* __restrict__ A, int lda,
                                               const u16* __restrict__ Bt, int ldb,
                                               void* __restrict__ Cv, int ldc, int Nreal,
                                               const float* __restrict__ bias, int Kpad) {
    __shared__ u16 lA[128 * 32];
    __shared__ u16 lB[128 * 32];
    const int tid = threadIdx.x;
    const int bn = blockIdx.x, bm = blockIdx.y;
    const long row0 = (long)bm * 128;
    const u16* Ab = A + row0 * lda;
    const u16* Bb = Bt + (long)bn * 128 * ldb;
    const int lane = tid & 63, wave = tid >> 6;
    const int wr = wave >> 1, wc = wave & 1;
    const int lr = lane & 15, ko = (lane >> 4) * 8;
    f32x4 acc[4][4] = {};

    for (int k0 = 0; k0 < Kpad; k0 += 32) {
#pragma unroll
        for (int i = 0; i < 2; ++i) {
            const int c = tid + 256 * i;
            const int e = c * 8;
            const int r = e >> 5, col = e & 31;
            __builtin_amdgcn_global_load_lds(
                (const __attribute__((address_space(1))) void*)(Ab + (long)r * lda + k0 + col),
                (__attribute__((address_space(3))) void*)(&lA[e]), 16, 0, 0);
            __builtin_amdgcn_global_load_lds(
                (const __attribute__((address_space(1))) void*)(Bb + (long)r * ldb + k0 + col),
                (__attribute__((address_space(3))) void*)(&lB[e]), 16, 0, 0);
        }
        __syncthreads();
        short8 af[4], bfr[4];
#pragma unroll
        for (int i = 0; i < 4; ++i) {
            af[i]  = *(const short8*)&lA[(wr * 64 + i * 16 + lr) * 32 + ko];
            bfr[i] = *(const short8*)&lB[(wc * 64 + i * 16 + lr) * 32 + ko];
        }
#pragma unroll
        for (int i = 0; i < 4; ++i)
#pragma unroll
            for (int j = 0; j < 4; ++j)
                acc[i][j] = __builtin_amdgcn_mfma_f32_16x16x32_bf16(af[i], bfr[j], acc[i][j], 0, 0, 0);
        __syncthreads();
    }

    const int r4 = (lane >> 4) * 4;
    const int cl = lane & 15;
#pragma unroll
    for (int i = 0; i < 4; ++i) {
#pragma unroll
        for (int j = 0; j < 4; ++j) {
            const int colg = bn * 128 + wc * 64 + j * 16 + cl;
            if (colg >= Nreal) continue;
            const float bv = bias ? bias[colg] : 0.f;
#pragma unroll
            for (int v = 0; v < 4; ++v) {
                const long rowg = row0 + wr * 64 + i * 16 + r4 + v;
                const float val = acc[i][j][v] + bv;
                if (MODE == 0) {
                    ((float*)Cv)[rowg * (long)ldc + colg] = val;
                } else if (MODE == 1) {
                    ((u16*)Cv)[rowg * (long)ldc + colg] = f2bf(val);
                } else {
                    const int tt = (int)(rowg >> 7), bb = (int)(rowg & 127);
                    ((float*)Cv)[((long)bb * QL_ + tt + 1) * (long)V_ + colg] = val;
                }
            }
        }
    }
}

// ---------------------------------------------------------------- persistent encoder (v3)
// 16 blocks: task = bid>>2, bslice = bid&3 (32 batches). Per step:
//   gh+bhh = MFMA_f16( [h_hi|h_lo][32 x 320], WhhP[1024 x 320]^T )
// v3: W streams DIRECTLY global->VGPR per wave (contiguous 1KB half8 tiles) — no LDS staging,
// no per-kt barriers. Only 2 barriers/step: (a) after all h reads, (b) after h writes.
// gi is TRANSPOSED time-major: gi_T[col(1024)][t*128+b] bf16 (bih already folded in) -> gate
// inputs are 15 x 8B vector loads, prefetched before the MFMA phase.
__global__ __launch_bounds__(512) void enc_persist(
        const u16* __restrict__ Wp_all,
        const u16* __restrict__ gi_tf, const u16* __restrict__ gi_tb,
        const u16* __restrict__ gi_af, const u16* __restrict__ gi_ab,
        u16* __restrict__ text_rep, float* __restrict__ h_fin) {
    const int task = blockIdx.x >> 2, bslice = blockIdx.x & 3;
    const u16* Wp = Wp_all + (size_t)task * WPT_;
    const u16* gi; int T, Tloop, rev;
    if (task == 0)      { gi = gi_tf; T = 400; Tloop = 400; rev = 0; }
    else if (task == 1) { gi = gi_tb; T = 400; Tloop = 400; rev = 1; }
    else if (task == 2) { gi = gi_af; T = 50;  Tloop = 50;  rev = 0; }
    else                { gi = gi_ab; T = 50;  Tloop = 1;   rev = 1; }
    const size_t BT = (size_t)B_ * T;

    __shared__ u16 hHi[10 * 32 * 32];   // 20KB: h_hi fp16, [kt][row][kk]; k=300 = bias col 1.0
    __shared__ u16 hLo[10 * 32 * 32];   // 20KB: h_lo fp16

    const int tid = threadIdx.x, lane = tid & 63, wave = tid >> 6;
    const int wm = wave >> 2, wn = wave & 3;       // wm: batch half, wn: column-group lane
    const int lr = lane & 15, ko8 = (lane >> 4) * 8;
    const int q = lane >> 4, jl = lane & 15;
    const int bg0 = bslice * 32 + wm * 16 + q * 4; // batch base for the 4 v-slots

    for (int i = tid; i < 10240; i += 512) { hHi[i] = 0; hLo[i] = 0; }
    __syncthreads();   // r8 race fix: zero-fill globally visible before bias write
    if (tid < 32) hHi[(9 * 32 + tid) * 32 + 12] = 0x3C00;  // fp16(1.0) at k=300
    __syncthreads();

    float hprev[20];
#pragma unroll
    for (int i = 0; i < 20; ++i) hprev[i] = 0.f;

    for (int t = 0; t < Tloop; ++t) {
        const int te = rev ? (T - 1 - t) : t;
        // ---- prefetch gate inputs (hidden under MFMA phase)
        u16x4 gpre[5][3];
#pragma unroll
        for (int gx = 0; gx < 5; ++gx) {
            const int G = wn + 4 * gx;
            if (G < 19) {
                const int j = G * 16 + jl;
#pragma unroll
                for (int gate = 0; gate < 3; ++gate)
                    gpre[gx][gate] = *(const u16x4*)&gi[(size_t)(gate * 300 + j) * BT + (size_t)te * B_ + bg0];
            }
        }
        // ---- MFMA phase: B direct from global, A from LDS; no barriers
        f32x4 acc[15] = {};
#pragma unroll 2
        for (int kt = 0; kt < 10; ++kt) {
            half8 afh = *(const half8*)&hHi[((kt * 32) + wm * 16 + lr) * 32 + ko8];
            half8 afl = *(const half8*)&hLo[((kt * 32) + wm * 16 + lr) * 32 + ko8];
#pragma unroll
            for (int gx = 0; gx < 5; ++gx) {
                const int G = wn + 4 * gx;
                if (G < 19) {
#pragma unroll
                    for (int gate = 0; gate < 3; ++gate) {
                        const int tn = 19 * gate + G;
                        half8 bf = *(const half8*)&Wp[((size_t)kt * 1024 + tn * 16 + lr) * 32 + ko8];
                        acc[gx * 3 + gate] = __builtin_amdgcn_mfma_f32_16x16x32_f16(afh, bf, acc[gx * 3 + gate], 0, 0, 0);
                        acc[gx * 3 + gate] = __builtin_amdgcn_mfma_f32_16x16x32_f16(afl, bf, acc[gx * 3 + gate], 0, 0, 0);
                    }
                }
            }
        }
        __syncthreads();   // all waves' h reads complete before any h write
        // ---- gates: pure per-thread
#pragma unroll
        for (int gx = 0; gx < 5; ++gx) {
            const int G = wn + 4 * gx;
            if (G >= 19) continue;
            const int j = G * 16 + jl;
            if (j >= 300) continue;
#pragma unroll
            for (int v = 0; v < 4; ++v) {
                const int batch = wm * 16 + q * 4 + v;
                const int bglob = bslice * 32 + batch;
                float r_ = sigm(bf2f(gpre[gx][0][v]) + acc[gx * 3 + 0][v]);
                float z_ = sigm(bf2f(gpre[gx][1][v]) + acc[gx * 3 + 1][v]);
                float x = bf2f(gpre[gx][2][v]) + r_ * acc[gx * 3 + 2][v];
                x = fminf(fmaxf(x, -15.f), 15.f);
                float e = __expf(2.f * x);
                float n_ = (e - 1.f) / (e + 1.f);
                float hn = (1.f - z_) * n_ + z_ * hprev[gx * 4 + v];
                hprev[gx * 4 + v] = hn;
                _Float16 hh = (_Float16)hn;
                float hhf = (float)hh;
                _Float16 hl = (_Float16)(hn - hhf);
                u16 uhh, uhl;
                __builtin_memcpy(&uhh, &hh, 2);
                __builtin_memcpy(&uhl, &hl, 2);
                const int hidx = ((j >> 5) * 32 + batch) * 32 + (j & 31);
                hHi[hidx] = uhh;
                hLo[hidx] = uhl;
                if (task < 2) text_rep[((size_t)bglob * TL_ + te) * K2P_ + task * 300 + j] = f2bf(hn);
            }
        }
        __syncthreads();   // h writes visible before next step's reads
    }
    if (task >= 2) {
#pragma unroll
        for (int gx = 0; gx < 5; ++gx) {
            const int G = wn + 4 * gx; if (G >= 19) continue;
            const int j = G * 16 + jl; if (j >= 300) continue;
#pragma unroll
            for (int v = 0; v < 4; ++v) {
                const int bglob = bslice * 32 + wm * 16 + q * 4 + v;
                h_fin[(size_t)(task - 2) * 38400 + (size_t)bglob * 300 + j] = hprev[gx * 4 + v];
            }
        }
    }
}

// ---------------------------------------------------------------- hidden0 = ans_rep[:,-1,:] @ trans_W + trans_b
__global__ __launch_bounds__(256) void trans_hidden(const float* __restrict__ h_fin,
                                                    const float* __restrict__ trans_W,
                                                    const float* __restrict__ trans_b,
                                                    float* __restrict__ h_dec, u16* __restrict__ A_dec0) {
    int b = blockIdx.x, tid = threadIdx.x;
    __shared__ float si[600];
    const float* af = h_fin + (size_t)b * 300;            // ans-fwd final
    const float* ab = h_fin + 38400 + (size_t)b * 300;    // ans-bwd (single step)
    for (int i = tid; i < 300; i += 256) { si[i] = af[i]; si[300 + i] = ab[i]; }
    __syncthreads();
    for (int jj = tid; jj < 300; jj += 256) {
        float acc = trans_b[jj];
        for (int k = 0; k < 600; ++k) acc += si[k] * trans_W[k * 300 + jj];
        h_dec[(size_t)b * 300 + jj] = acc;
        A_dec0[(size_t)b * KDP_ + 900 + jj] = f2bf(acc);
    }
}

// ---------------------------------------------------------------- attention (one block per batch row)
__global__ __launch_bounds__(256) void attn_step(int t, const float* __restrict__ h_dec,
                                                 const float* __restrict__ Wk, const float* __restrict__ av,
                                                 const float* __restrict__ qproj, const u16* __restrict__ text_rep,
                                                 u16* __restrict__ A_dec_t, u16* __restrict__ A_out) {
    const int b = blockIdx.x, tid = threadIdx.x, lane = tid & 63, wave = tid >> 6;
    __shared__ float sh[300], hwk[300], sc[400], red[8];
    for (int i = tid; i < 300; i += 256) sh[i] = h_dec[(size_t)b * 300 + i];
    __syncthreads();
    for (int jj = tid; jj < 300; jj += 256) {
        float acc = 0.f;
        for (int k = 0; k < 300; ++k) acc += sh[k] * Wk[k * 300 + jj];
        hwk[jj] = acc;
    }
    __syncthreads();
    for (int s = wave; s < 400; s += 4) {
        const float* qp = qproj + ((size_t)b * TL_ + s) * 300;
        float p = 0.f;
        for (int d = lane; d < 300; d += 64) {
            float e = qp[d] + hwk[d];
            e = fminf(fmaxf(e, -15.f), 15.f);
            float ex = __expf(2.f * e);
            p += ((ex - 1.f) / (ex + 1.f)) * av[d];
        }
#pragma unroll
        for (int off = 32; off > 0; off >>= 1) p += __shfl_down(p, off);
        if (lane == 0) sc[s] = p;
    }
    __syncthreads();
    float m = -1e30f;
    for (int i = tid; i < 400; i += 256) m = fmaxf(m, sc[i]);
#pragma unroll
    for (int off = 32; off > 0; off >>= 1) m = fmaxf(m, __shfl_down(m, off));
    if (lane == 0) red[wave] = m;
    __syncthreads();
    m = fmaxf(fmaxf(red[0], red[1]), fmaxf(red[2], red[3]));
    float ssum = 0.f;
    for (int i = tid; i < 400; i += 256) { float e = __expf(sc[i] - m); sc[i] = e; ssum += e; }
#pragma unroll
    for (int off = 32; off > 0; off >>= 1) ssum += __shfl_down(ssum, off);
    if (lane == 0) red[4 + wave] = ssum;
    __syncthreads();
    const float inv = 1.f / (red[4] + red[5] + red[6] + red[7]);
    for (int e0 = tid; e0 < 600; e0 += 256) {
        float acc = 0.f;
        for (int s = 0; s < 400; ++s) acc += sc[s] * bf2f(text_rep[((size_t)b * TL_ + s) * K2P_ + e0]);
        u16 wv = f2bf(acc * inv);
        A_dec_t[(size_t)b * KDP_ + 300 + e0] = wv;
        A_out[((size_t)t * 128 + b) * KDP_ + 300 + e0] = wv;
    }
}

// ---------------------------------------------------------------- decoder GRU gates
__global__ __launch_bounds__(256) void dec_gate(int t, const float* __restrict__ g_all,
                                                float* __restrict__ h_dec,
                                                u16* __restrict__ A_dec, u16* __restrict__ A_out) {
    int idx = blockIdx.x * 256 + threadIdx.x;
    if (idx >= 128 * 300) return;
    int b = idx / 300, j = idx % 300;
    const float* g = g_all + (size_t)b * NDP_;
    float r = sigm(g[j] + g[900 + j]);
    float z = sigm(g[300 + j] + g[1200 + j]);
    float n = tanhf(g[600 + j] + r * g[1500 + j]);
    float hp = h_dec[idx];
    float hn = (1.f - z) * n + z * hp;
    h_dec[idx] = hn;
    u16 u = f2bf(hn);
    A_out[((size_t)t * 128 + b) * KDP_ + j] = u;
    if (t < 30) A_dec[((size_t)(t + 1) * 128 + b) * KDP_ + 900 + j] = u;
}

__global__ __launch_bounds__(256) void zero_t0(float* __restrict__ out) {
    int i = blockIdx.x * 256 + threadIdx.x;
    if (i < 128 * V_) {
        int b = i / V_, v = i % V_;
        out[(size_t)b * QL_ * V_ + v] = 0.f;
    }
}

// ================================================================ host
extern "C" void kernel_launch(void* const* d_in, const int* in_sizes, int n_in,
                              void* d_out, int out_size, void* d_ws, size_t ws_size,
                              hipStream_t stream) {
    (void)in_sizes; (void)n_in; (void)out_size;
    const int*   text      = (const int*)d_in[0];
    const int*   answer    = (const int*)d_in[1];
    const int*   question  = (const int*)d_in[2];
    const float* embedding = (const float*)d_in[3];
    const float* te_Wih_f = (const float*)d_in[4],  *te_Whh_f = (const float*)d_in[5];
    const float* te_bih_f = (const float*)d_in[6],  *te_bhh_f = (const float*)d_in[7];
    const float* te_Wih_b = (const float*)d_in[8],  *te_Whh_b = (const float*)d_in[9];
    const float* te_bih_b = (const float*)d_in[10], *te_bhh_b = (const float*)d_in[11];
    const float* ae_Wih_f = (const float*)d_in[12], *ae_Whh_f = (const float*)d_in[13];
    const float* ae_bih_f = (const float*)d_in[14], *ae_bhh_f = (const float*)d_in[15];
    const float* ae_Wih_b = (const float*)d_in[16], *ae_Whh_b = (const float*)d_in[17];
    const float* ae_bih_b = (const float*)d_in[18], *ae_bhh_b = (const float*)d_in[19];
    const float* trans_W  = (const float*)d_in[20], *trans_b  = (const float*)d_in[21];
    const float* attn_Wk  = (const float*)d_in[22], *attn_Wq  = (const float*)d_in[23];
    const float* attn_b   = (const float*)d_in[24], *attn_v   = (const float*)d_in[25];
    const float* dec_Wih  = (const float*)d_in[26], *dec_Whh  = (const float*)d_in[27];
    const float* dec_bih  = (const float*)d_in[28], *dec_bhh  = (const float*)d_in[29];
    const float* out_W    = (const float*)d_in[30], *out_b    = (const float*)d_in[31];
    float* out = (float*)d_out;

    // ---- workspace carve
    char* w = (char*)d_ws; size_t off = 0;
    auto alloc = [&](size_t bytes) -> void* { void* p = w + off; off += (bytes + 255) & ~(size_t)255; return p; };
    u16* WihT_tf = (u16*)alloc(1024 * EP_ * 2);
    u16* WihT_tb = (u16*)alloc(1024 * EP_ * 2);
    u16* WihT_af = (u16*)alloc(1024 * EP_ * 2);
    u16* WihT_ab = (u16*)alloc(1024 * EP_ * 2);
    u16* WqT     = (u16*)alloc(384 * K2P_ * 2);
    u16* outWT   = (u16*)alloc((size_t)30080 * KDP_ * 2);
    u16* decBT   = (u16*)alloc((size_t)NDP_ * KDP_ * 2);
    float* decBias = (float*)alloc(NDP_ * 4);
    u16* WhhPt   = (u16*)alloc((size_t)4 * WPT_ * 2);
    u16* textEmb = (u16*)alloc((size_t)MT_ * EP_ * 2);       // dead after gi GEMMs
    u16* ansEmb  = (u16*)alloc((size_t)MA_ * EP_ * 2);       // dead after gi GEMMs
    u16* gi_tf   = (u16*)alloc((size_t)1024 * MT_ * 2);      // gi^T [col][t*128+b]; dead after enc
    u16* gi_tb   = (u16*)alloc((size_t)1024 * MT_ * 2);
    u16* gi_af   = (u16*)alloc((size_t)1024 * MA_ * 2);
    u16* gi_ab   = (u16*)alloc((size_t)1024 * MA_ * 2);
    u16* text_rep = (u16*)alloc((size_t)MT_ * K2P_ * 2);
    float* h_fin = (float*)alloc((size_t)2 * 128 * 300 * 4);
    float* h_dec = (float*)alloc((size_t)128 * 300 * 4);
    u16* A_dec   = (u16*)alloc((size_t)MD_ * KDP_ * 2);
    u16* A_out   = (u16*)alloc((size_t)MD_ * KDP_ * 2);
    float* gi_gh = (float*)alloc((size_t)128 * NDP_ * 4);
    // qproj (61.4MB f32) aliases the dead-after-enc textEmb+ansEmb+gi_tf region (written after enc)
    float* qproj = (float*)textEmb;
    const size_t need = off;
    size_t zbytes = need <= ws_size ? need : ws_size;

    hipMemsetAsync(d_ws, 0, zbytes, stream);

    // ---- weight prep
    transpose_cvt<<<dim3(10, 29), 256, 0, stream>>>(te_Wih_f, 300, 900, WihT_tf, EP_, 0, 0);
    transpose_cvt<<<dim3(10, 29), 256, 0, stream>>>(te_Wih_b, 300, 900, WihT_tb, EP_, 0, 0);
    transpose_cvt<<<dim3(10, 29), 256, 0, stream>>>(ae_Wih_f, 300, 900, WihT_af, EP_, 0, 0);
    transpose_cvt<<<dim3(10, 29), 256, 0, stream>>>(ae_Wih_b, 300, 900, WihT_ab, EP_, 0, 0);
    set_wih_bias<<<4, 256, 0, stream>>>(WihT_tf, te_bih_f);
    set_wih_bias<<<4, 256, 0, stream>>>(WihT_tb, te_bih_b);
    set_wih_bias<<<4, 256, 0, stream>>>(WihT_af, ae_bih_f);
    set_wih_bias<<<4, 256, 0, stream>>>(WihT_ab, ae_bih_b);
    prep_whh<<<dim3(1024, 4), 320, 0, stream>>>(te_Whh_f, te_Whh_b, ae_Whh_f, ae_Whh_b,
                                                te_bhh_f, te_bhh_b, ae_bhh_f, ae_bhh_b, WhhPt);
    transpose_cvt<<<dim3(19, 10), 256, 0, stream>>>(attn_Wq, 600, 300, WqT, K2P_, 0, 0);
    transpose_cvt<<<dim3(38, 938), 256, 0, stream>>>(out_W, 1200, V_, outWT, KDP_, 0, 0);
    transpose_cvt<<<dim3(29, 29), 256, 0, stream>>>(dec_Wih, 900, 900, decBT, KDP_, 0, 0);
    transpose_cvt<<<dim3(10, 29), 256, 0, stream>>>(dec_Whh, 300, 900, decBT, KDP_, 900, 900);
    build_dec_bias<<<8, 256, 0, stream>>>(dec_bih, dec_bhh, decBias);

    // ---- embedding gathers (time-major, ones-column at 300)
    gather_tm<<<MT_, 256, 0, stream>>>(text, embedding, textEmb, TL_);
    gather_tm<<<MA_, 256, 0, stream>>>(answer, embedding, ansEmb, AL_);
    gather_q<<<MD_, 256, 0, stream>>>(question, embedding, A_dec, A_out);

    // ---- gi^T = WihT(+bih col) @ emb^T   [1024 x B*T] bf16, bih folded via ones-column
    gemm_bt<1><<<dim3(400, 8), 256, 0, stream>>>(WihT_tf, EP_, textEmb, EP_, gi_tf, MT_, MT_, nullptr, EP_);
    gemm_bt<1><<<dim3(400, 8), 256, 0, stream>>>(WihT_tb, EP_, textEmb, EP_, gi_tb, MT_, MT_, nullptr, EP_);
    gemm_bt<1><<<dim3(50, 8),  256, 0, stream>>>(WihT_af, EP_, ansEmb, EP_, gi_af, MA_, MA_, nullptr, EP_);
    gemm_bt<1><<<dim3(50, 8),  256, 0, stream>>>(WihT_ab, EP_, ansEmb, EP_, gi_ab, MA_, MA_, nullptr, EP_);

    // ---- persistent encoder (16 independent blocks)
    enc_persist<<<16, 512, 0, stream>>>(WhhPt, gi_tf, gi_tb, gi_af, gi_ab, text_rep, h_fin);

    // ---- decoder init + qproj (qproj aliases dead gi/emb region)
    trans_hidden<<<128, 256, 0, stream>>>(h_fin, trans_W, trans_b, h_dec, A_dec);
    gemm_bt<0><<<dim3(3, 400), 256, 0, stream>>>(text_rep, K2P_, WqT, K2P_, qproj, 300, 300, attn_b, K2P_);

    // ---- decode loop
    for (int t = 0; t < QL_ - 1; ++t) {
        attn_step<<<128, 256, 0, stream>>>(t, h_dec, attn_Wk, attn_v, qproj, text_rep,
                                           A_dec + (size_t)t * 128 * KDP_, A_out);
        gemm_bt<0><<<dim3(15, 1), 256, 0, stream>>>(A_dec + (size_t)t * 128 * KDP_, KDP_,
                                                    decBT, KDP_, gi_gh, NDP_, 1800, decBias, KDP_);
        dec_gate<<<150, 256, 0, stream>>>(t, gi_gh, h_dec, A_dec, A_out);
    }

    // ---- logits
    gemm_bt<2><<<dim3(235, 31), 256, 0, stream>>>(A_out, KDP_, outWT, KDP_, d_out, 0, V_, out_b, KDP_);
    zero_t0<<<(128 * V_ + 255) / 256, 256, 0, stream>>>(out);
}